// Round 1
// 2967.067 us; speedup vs baseline: 1.6501x; 1.6501x over previous
//
#include <hip/hip_runtime.h>

typedef unsigned short u16;
typedef unsigned int u32;

#define OVF_CAP 8192

// ---------- bf16 helpers (used only for ws-resident core/gate intermediates) ----------
__device__ __forceinline__ u16 f2bf(float f) {
  u32 u = __float_as_uint(f);
  u32 r = u + 0x7fffu + ((u >> 16) & 1u);
  return (u16)(r >> 16);
}
__device__ __forceinline__ void cvt8(uint4 u, float* f) {
  f[0] = __uint_as_float(u.x << 16);
  f[1] = __uint_as_float(u.x & 0xffff0000u);
  f[2] = __uint_as_float(u.y << 16);
  f[3] = __uint_as_float(u.y & 0xffff0000u);
  f[4] = __uint_as_float(u.z << 16);
  f[5] = __uint_as_float(u.z & 0xffff0000u);
  f[6] = __uint_as_float(u.w << 16);
  f[7] = __uint_as_float(u.w & 0xffff0000u);
}
__device__ __forceinline__ u32 pack2(float a, float b) {
  return (u32)f2bf(a) | ((u32)f2bf(b) << 16);
}

struct GatherSrc {
  const float* base[4];
  const int* idx[4];  // nullptr => identity (row index)
};

// ---------- pass 1: gathered concat GEMM -> core/gate (bf16 in ws) + BN stats ----------
// Block: 256 threads, 64 rows. Thread computes 4 rows x 8 cols (of 128 = core|gate).
template <int NSEG>
__global__ __launch_bounds__(256) void pass1_gemm(
    GatherSrc gs, const float* __restrict__ Wc, const float* __restrict__ Wg,
    u16* __restrict__ outC, u16* __restrict__ outG, float* __restrict__ stats,
    int R) {
  __shared__ float msg[64][68];      // [row][k within 64-chunk], padded
  __shared__ float wt[64][132];      // [k][core 0..63 | gate 64..127], padded
  __shared__ float sstat[2][2][64];  // [mat][sum/sumsq][col]
  __shared__ int rowidx[NSEG][64];

  const int t = threadIdx.x;
  const int e0 = blockIdx.x * 64;

  for (int i = t; i < 256; i += 256) ((float*)sstat)[i] = 0.0f;
  if (t < 64) {
    int rc = e0 + t;
    if (rc > R - 1) rc = R - 1;
#pragma unroll
    for (int sg = 0; sg < NSEG; ++sg) {
      const int* ip = gs.idx[sg];
      rowidx[sg][t] = ip ? ip[rc] : rc;
    }
  }

  float acc[4][8];
#pragma unroll
  for (int r = 0; r < 4; ++r)
#pragma unroll
    for (int j = 0; j < 8; ++j) acc[r][j] = 0.0f;

  const int cg = t & 15;        // col-group (8 cols) within 128
  const int r0 = (t >> 4) * 4;  // base row of the thread's 4 rows
  const int c8 = cg * 8;

  for (int kt = 0; kt < NSEG; ++kt) {
    __syncthreads();
    // stage msg chunk kt (gathered rows, 64 fp32 each): 1024 float4 slots
    {
      const float* base = gs.base[kt];
#pragma unroll
      for (int i = 0; i < 4; ++i) {
        int s = t + i * 256;
        int r = s >> 4, q4 = (s & 15) * 4;
        *(float4*)&msg[r][q4] =
            *(const float4*)(base + (size_t)rowidx[kt][r] * 64 + q4);
      }
    }
    // stage W tile: rows kt*64..+63 of Wc and Wg: 2048 float4 slots
    {
#pragma unroll
      for (int i = 0; i < 8; ++i) {
        int s = t + i * 256;
        int mat = s >> 10;
        int kk = (s >> 4) & 63;
        int q4 = (s & 15) * 4;
        const float* wsrc = (mat ? Wg : Wc) + (size_t)(kt * 64 + kk) * 64 + q4;
        *(float4*)&wt[kk][mat * 64 + q4] = *(const float4*)wsrc;
      }
    }
    __syncthreads();
    // compute: 4 rows x 8 cols, k over 64 in steps of 4
    for (int k = 0; k < 64; k += 4) {
      float a[4][4];
#pragma unroll
      for (int r = 0; r < 4; ++r)
        *(float4*)&a[r][0] = *(const float4*)&msg[r0 + r][k];
#pragma unroll
      for (int kk = 0; kk < 4; ++kk) {
        float w[8];
        *(float4*)&w[0] = *(const float4*)&wt[k + kk][c8];
        *(float4*)&w[4] = *(const float4*)&wt[k + kk][c8 + 4];
#pragma unroll
        for (int r = 0; r < 4; ++r) {
          float m = a[r][kk];
#pragma unroll
          for (int j = 0; j < 8; ++j) acc[r][j] = fmaf(m, w[j], acc[r][j]);
        }
      }
    }
  }

  // epilogue: store bf16 intermediates + accumulate stats
  const int mat = cg >> 3;
  const int cb = (cg & 7) * 8;  // col base within 64
  u16* outp = mat ? outG : outC;
  float ssum[8], ssq[8];
#pragma unroll
  for (int j = 0; j < 8; ++j) {
    ssum[j] = 0.0f;
    ssq[j] = 0.0f;
  }
#pragma unroll
  for (int r = 0; r < 4; ++r) {
    int row = e0 + r0 + r;
    if (row < R) {
      uint4 u;
      u.x = pack2(acc[r][0], acc[r][1]);
      u.y = pack2(acc[r][2], acc[r][3]);
      u.z = pack2(acc[r][4], acc[r][5]);
      u.w = pack2(acc[r][6], acc[r][7]);
      *(uint4*)(outp + (size_t)row * 64 + cb) = u;
#pragma unroll
      for (int j = 0; j < 8; ++j) {
        ssum[j] += acc[r][j];
        ssq[j] += acc[r][j] * acc[r][j];
      }
    }
  }
#pragma unroll
  for (int j = 0; j < 8; ++j) {
    atomicAdd(&sstat[mat][0][cb + j], ssum[j]);
    atomicAdd(&sstat[mat][1][cb + j], ssq[j]);
  }
  __syncthreads();
  {
    int m2 = t >> 7, s2 = (t >> 6) & 1, c = t & 63;
    atomicAdd(&stats[m2 * 128 + s2 * 64 + c], sstat[m2][s2][c]);
  }
}

// ---------- fold BN stats + gamma/beta into per-col scale/shift ----------
__global__ void statprep(float* __restrict__ stats, const float* __restrict__ gc,
                         const float* __restrict__ bc, const float* __restrict__ gg,
                         const float* __restrict__ bg, float rn) {
  int t = threadIdx.x;
  if (t >= 128) return;
  int mat = t >> 6, c = t & 63;
  float sum = stats[mat * 128 + c];
  float sumsq = stats[mat * 128 + 64 + c];
  float mean = sum * rn;
  float var = sumsq * rn - mean * mean;
  float inv = rsqrtf(var + 1e-5f);
  const float* gp = mat ? gg : gc;
  const float* bp = mat ? bg : bc;
  float scale = gp[c] * inv;
  float shift = bp[c] - mean * scale;
  stats[256 + mat * 128 + c] = scale;
  stats[256 + mat * 128 + 64 + c] = shift;
}

// ---------- ELL build: per-segment member lists (no scan needed) ----------
template <int CAP>
__global__ __launch_bounds__(256) void ell_fill(const int* __restrict__ seg,
                                                int* __restrict__ cnt,
                                                int* __restrict__ list,
                                                int* __restrict__ ovf, int R) {
  int e = blockIdx.x * 256 + threadIdx.x;
  if (e >= R) return;
  int s = seg[e];
  int pos = atomicAdd(&cnt[s], 1);
  if (pos < CAP) {
    list[(size_t)s * CAP + pos] = e;
  } else {
    int o = atomicAdd(&ovf[0], 1);
    if (o < OVF_CAP) ovf[1 + o] = e;
  }
}

// ---------- pass 2 (gather form): BN + silu*sigmoid, register-accumulate per
// segment, single coalesced non-atomic row write. 8 lanes per segment. ----------
template <int CAP>
__global__ __launch_bounds__(256) void seg_gather(
    const u16* __restrict__ coreB, const u16* __restrict__ gateB,
    const float* __restrict__ stats, const int* __restrict__ cnt,
    const int* __restrict__ list, float* __restrict__ accum, int S) {
  int gid = blockIdx.x * 256 + threadIdx.x;
  int s = gid >> 3;
  if (s >= S) return;
  int cb = (gid & 7) * 8;
  float scC[8], shC[8], scG[8], shG[8];
  *(float4*)&scC[0] = *(const float4*)&stats[256 + cb];
  *(float4*)&scC[4] = *(const float4*)&stats[256 + cb + 4];
  *(float4*)&shC[0] = *(const float4*)&stats[320 + cb];
  *(float4*)&shC[4] = *(const float4*)&stats[320 + cb + 4];
  *(float4*)&scG[0] = *(const float4*)&stats[384 + cb];
  *(float4*)&scG[4] = *(const float4*)&stats[384 + cb + 4];
  *(float4*)&shG[0] = *(const float4*)&stats[448 + cb];
  *(float4*)&shG[4] = *(const float4*)&stats[448 + cb + 4];

  int n = cnt[s];
  if (n > CAP) n = CAP;
  const int* lp = list + (size_t)s * CAP;
  float acc[8];
#pragma unroll
  for (int j = 0; j < 8; ++j) acc[j] = 0.0f;

  int m = 0;
  for (; m + 2 <= n; m += 2) {  // 2-way unroll for load ILP
    int r0 = lp[m], r1 = lp[m + 1];
    uint4 uc0 = *(const uint4*)(coreB + (size_t)r0 * 64 + cb);
    uint4 ug0 = *(const uint4*)(gateB + (size_t)r0 * 64 + cb);
    uint4 uc1 = *(const uint4*)(coreB + (size_t)r1 * 64 + cb);
    uint4 ug1 = *(const uint4*)(gateB + (size_t)r1 * 64 + cb);
    float c[8], g[8];
    cvt8(uc0, c);
    cvt8(ug0, g);
#pragma unroll
    for (int j = 0; j < 8; ++j) {
      float x = fmaf(c[j], scC[j], shC[j]);
      float sx = x / (1.0f + __expf(-x));
      float y = fmaf(g[j], scG[j], shG[j]);
      float sy = 1.0f / (1.0f + __expf(-y));
      acc[j] += sx * sy;
    }
    cvt8(uc1, c);
    cvt8(ug1, g);
#pragma unroll
    for (int j = 0; j < 8; ++j) {
      float x = fmaf(c[j], scC[j], shC[j]);
      float sx = x / (1.0f + __expf(-x));
      float y = fmaf(g[j], scG[j], shG[j]);
      float sy = 1.0f / (1.0f + __expf(-y));
      acc[j] += sx * sy;
    }
  }
  if (m < n) {
    int r0 = lp[m];
    uint4 uc0 = *(const uint4*)(coreB + (size_t)r0 * 64 + cb);
    uint4 ug0 = *(const uint4*)(gateB + (size_t)r0 * 64 + cb);
    float c[8], g[8];
    cvt8(uc0, c);
    cvt8(ug0, g);
#pragma unroll
    for (int j = 0; j < 8; ++j) {
      float x = fmaf(c[j], scC[j], shC[j]);
      float sx = x / (1.0f + __expf(-x));
      float y = fmaf(g[j], scG[j], shG[j]);
      float sy = 1.0f / (1.0f + __expf(-y));
      acc[j] += sx * sy;
    }
  }
  float* ap = accum + (size_t)s * 64 + cb;
  *(float4*)ap = *(float4*)&acc[0];
  *(float4*)(ap + 4) = *(float4*)&acc[4];
}

// ---------- overflow fallback (normally zero work): atomic adds for members
// that exceeded ELL capacity ----------
__global__ __launch_bounds__(256) void ovf_apply(
    const int* __restrict__ ovf, const int* __restrict__ seg,
    const u16* __restrict__ coreB, const u16* __restrict__ gateB,
    const float* __restrict__ stats, float* __restrict__ accum) {
  int n = ovf[0];
  if (n > OVF_CAP) n = OVF_CAP;
  int total = n * 8;
  for (int gid = blockIdx.x * 256 + threadIdx.x; gid < total;
       gid += gridDim.x * 256) {
    int i = gid >> 3;
    int cb = (gid & 7) * 8;
    int r = ovf[1 + i];
    int s = seg[r];
    uint4 uc = *(const uint4*)(coreB + (size_t)r * 64 + cb);
    uint4 ug = *(const uint4*)(gateB + (size_t)r * 64 + cb);
    float c[8], g[8];
    cvt8(uc, c);
    cvt8(ug, g);
    float* ap = accum + (size_t)s * 64 + cb;
#pragma unroll
    for (int j = 0; j < 8; ++j) {
      float x = fmaf(c[j], stats[256 + cb + j], stats[320 + cb + j]);
      float sx = x / (1.0f + __expf(-x));
      float y = fmaf(g[j], stats[384 + cb + j], stats[448 + cb + j]);
      float sy = 1.0f / (1.0f + __expf(-y));
      atomicAdd(ap + j, sx * sy);
    }
  }
}

// ---------- pass 2 (atomic scatter form) — fallback if ws too small ----------
__global__ __launch_bounds__(256) void pass2_scatter(
    const u16* __restrict__ coreB, const u16* __restrict__ gateB,
    const float* __restrict__ stats, const int* __restrict__ seg,
    float* __restrict__ accum, int R) {
  int gid = blockIdx.x * 256 + threadIdx.x;
  if (gid >= R * 8) return;
  int r = gid >> 3;
  int cb = (gid & 7) * 8;
  uint4 uc = *(const uint4*)(coreB + (size_t)r * 64 + cb);
  uint4 ug = *(const uint4*)(gateB + (size_t)r * 64 + cb);
  float c[8], g[8];
  cvt8(uc, c);
  cvt8(ug, g);
  float scC[8], shC[8], scG[8], shG[8];
  *(float4*)&scC[0] = *(const float4*)&stats[256 + cb];
  *(float4*)&scC[4] = *(const float4*)&stats[256 + cb + 4];
  *(float4*)&shC[0] = *(const float4*)&stats[320 + cb];
  *(float4*)&shC[4] = *(const float4*)&stats[320 + cb + 4];
  *(float4*)&scG[0] = *(const float4*)&stats[384 + cb];
  *(float4*)&scG[4] = *(const float4*)&stats[384 + cb + 4];
  *(float4*)&shG[0] = *(const float4*)&stats[448 + cb];
  *(float4*)&shG[4] = *(const float4*)&stats[448 + cb + 4];
  int sg = seg[r];
  float* ap = accum + (size_t)sg * 64 + cb;
#pragma unroll
  for (int j = 0; j < 8; ++j) {
    float x = fmaf(c[j], scC[j], shC[j]);
    float sx = x / (1.0f + __expf(-x));  // silu
    float y = fmaf(g[j], scG[j], shG[j]);
    float sy = 1.0f / (1.0f + __expf(-y));  // sigmoid
    atomicAdd(ap + j, sx * sy);
  }
}

// ---------- pass 2 (angle stage): BN-gate + residual -> fp32 out ----------
__global__ __launch_bounds__(256) void pass2_final(
    const u16* __restrict__ coreB, const u16* __restrict__ gateB,
    const float* __restrict__ stats, const float* __restrict__ angle,
    float* __restrict__ outA, int R) {
  int gid = blockIdx.x * 256 + threadIdx.x;
  if (gid >= R * 8) return;
  int r = gid >> 3;
  int cb = (gid & 7) * 8;
  uint4 uc = *(const uint4*)(coreB + (size_t)r * 64 + cb);
  uint4 ug = *(const uint4*)(gateB + (size_t)r * 64 + cb);
  float c[8], g[8], a[8];
  cvt8(uc, c);
  cvt8(ug, g);
  *(float4*)&a[0] = *(const float4*)(angle + (size_t)r * 64 + cb);
  *(float4*)&a[4] = *(const float4*)(angle + (size_t)r * 64 + cb + 4);
  float scC[8], shC[8], scG[8], shG[8];
  *(float4*)&scC[0] = *(const float4*)&stats[256 + cb];
  *(float4*)&scC[4] = *(const float4*)&stats[256 + cb + 4];
  *(float4*)&shC[0] = *(const float4*)&stats[320 + cb];
  *(float4*)&shC[4] = *(const float4*)&stats[320 + cb + 4];
  *(float4*)&scG[0] = *(const float4*)&stats[384 + cb];
  *(float4*)&scG[4] = *(const float4*)&stats[384 + cb + 4];
  *(float4*)&shG[0] = *(const float4*)&stats[448 + cb];
  *(float4*)&shG[4] = *(const float4*)&stats[448 + cb + 4];
  float o[8];
#pragma unroll
  for (int j = 0; j < 8; ++j) {
    float x = fmaf(c[j], scC[j], shC[j]);
    float sx = x / (1.0f + __expf(-x));
    float y = fmaf(g[j], scG[j], shG[j]);
    float sy = 1.0f / (1.0f + __expf(-y));
    o[j] = sx * sy + a[j];
  }
  float* dst = outA + (size_t)r * 64 + cb;
  *(float4*)dst = *(float4*)&o[0];
  *(float4*)(dst + 4) = *(float4*)&o[4];
}

// ---------- small out-GEMM: dest = accum(fp32) @ W(fp32 64x64) + resid(fp32) ----------
__global__ __launch_bounds__(256) void outgemm(const float* __restrict__ accum,
                                               const float* __restrict__ W,
                                               const float* __restrict__ resid,
                                               float* __restrict__ dest, int R) {
  __shared__ float inl[64][68];
  __shared__ float wl[64][68];
  const int t = threadIdx.x;
  const int e0 = blockIdx.x * 64;
#pragma unroll
  for (int i = 0; i < 4; ++i) {  // stage W (64x64 fp32): 1024 float4 slots
    int s = t + i * 256;
    int kk = s >> 4, q4 = (s & 15) * 4;
    *(float4*)&wl[kk][q4] = *(const float4*)(W + (size_t)kk * 64 + q4);
  }
#pragma unroll
  for (int i = 0; i < 4; ++i) {  // stage input rows (fp32)
    int s = t + i * 256;
    int r = s >> 4, q4 = (s & 15) * 4;
    int row = e0 + r;
    if (row > R - 1) row = R - 1;
    *(float4*)&inl[r][q4] = *(const float4*)(accum + (size_t)row * 64 + q4);
  }
  __syncthreads();
  const int c4 = (t & 15) * 4;
  const int r0 = (t >> 4) * 4;
  float acc[4][4];
#pragma unroll
  for (int r = 0; r < 4; ++r)
#pragma unroll
    for (int j = 0; j < 4; ++j) acc[r][j] = 0.0f;
  for (int k = 0; k < 64; k += 4) {
    float a[4][4];
#pragma unroll
    for (int r = 0; r < 4; ++r)
      *(float4*)&a[r][0] = *(const float4*)&inl[r0 + r][k];
#pragma unroll
    for (int kk = 0; kk < 4; ++kk) {
      float w[4];
      *(float4*)&w[0] = *(const float4*)&wl[k + kk][c4];
#pragma unroll
      for (int r = 0; r < 4; ++r) {
        float m = a[r][kk];
#pragma unroll
        for (int j = 0; j < 4; ++j) acc[r][j] = fmaf(m, w[j], acc[r][j]);
      }
    }
  }
#pragma unroll
  for (int r = 0; r < 4; ++r) {
    int row = e0 + r0 + r;
    if (row < R) {
      float4 rv = *(const float4*)(resid + (size_t)row * 64 + c4);
      float4 o;
      o.x = acc[r][0] + rv.x;
      o.y = acc[r][1] + rv.y;
      o.z = acc[r][2] + rv.z;
      o.w = acc[r][3] + rv.w;
      *(float4*)(dest + (size_t)row * 64 + c4) = o;
    }
  }
}

extern "C" void kernel_launch(void* const* d_in, const int* in_sizes, int n_in,
                              void* d_out, int out_size, void* d_ws,
                              size_t ws_size, hipStream_t stream) {
  const float* vertex = (const float*)d_in[0];
  const float* edge = (const float*)d_in[1];
  const float* angle = (const float*)d_in[2];
  const int* eidx = (const int*)d_in[3];  // [2,E]: src then dst
  const int* kidx = (const int*)d_in[4];
  const int* iidx = (const int*)d_in[5];
  const int* jidx = (const int*)d_in[6];
  const float* WcA = (const float*)d_in[7];
  const float* WgA = (const float*)d_in[8];
  const float* WoA = (const float*)d_in[9];
  const float* WcB = (const float*)d_in[10];
  const float* WgB = (const float*)d_in[11];
  const float* WoB = (const float*)d_in[12];
  const float* WcC = (const float*)d_in[13];
  const float* WgC = (const float*)d_in[14];
  const float* g_ac = (const float*)d_in[15];
  const float* g_ag = (const float*)d_in[16];
  const float* g_bc = (const float*)d_in[17];
  const float* g_bg = (const float*)d_in[18];
  const float* g_nc = (const float*)d_in[19];
  const float* g_ng = (const float*)d_in[20];
  const float* b_ac = (const float*)d_in[21];
  const float* b_ag = (const float*)d_in[22];
  const float* b_bc = (const float*)d_in[23];
  const float* b_bg = (const float*)d_in[24];
  const float* b_nc = (const float*)d_in[25];
  const float* b_ng = (const float*)d_in[26];

  const int N = in_sizes[0] / 64;
  const int E = in_sizes[1] / 64;
  const int T = in_sizes[2] / 64;

  float* outV = (float*)d_out;
  float* outE = outV + (size_t)N * 64;
  float* outA = outE + (size_t)E * 64;

  // workspace layout: bf16 core/gate (max(E,T) rows) + shared fp32 accumulator
  // (max(N,E) rows) + stats + ELL segment lists
  size_t RT = (size_t)(E > T ? E : T);
  size_t RM = (size_t)(N > E ? N : E);
  u16* coreB = (u16*)d_ws;
  u16* gateB = coreB + RT * 64;
  float* accum = (float*)(gateB + RT * 64);  // RM x 64 fp32
  float* stats = accum + RM * 64;            // 3 stages x 512 floats
  float* statsA = stats;
  float* statsB = stats + 512;
  float* statsC = stats + 1024;

  // ELL structures after stats (zero region must be contiguous: stats..ovfB)
  const int CAPA = 40;  // src-degree ~ Poisson(E/N=12); P(>=40) ~ 1e-10
  const int CAPB = 12;  // k_idx-degree ~ Poisson(T/E=1); P(>=12) ~ 8e-10
  int* cntA = (int*)(stats + 1536);            // N ints
  int* cntB = cntA + N;                        // E ints
  int* ovfA = cntB + E;                        // 1 + OVF_CAP
  int* ovfB = ovfA + (1 + OVF_CAP);            // 1 + OVF_CAP
  int* listA = ovfB + (1 + OVF_CAP);           // N*CAPA (not zeroed)
  int* listB = listA + (size_t)N * CAPA;       // E*CAPB (not zeroed)
  size_t needed = (size_t)((char*)(listB + (size_t)E * CAPB) - (char*)d_ws);

  const int bE = (E + 63) / 64;
  const int bT = (T + 63) / 64;
  const int bN = (N + 63) / 64;
  const int sT = (int)(((size_t)T * 8 + 255) / 256);

  if (ws_size >= needed) {
    // ---- gather path: no accumulator memsets, no scatter atomics ----
    size_t zbytes = (size_t)((char*)listA - (char*)stats);  // stats+cnt+ovf
    hipMemsetAsync(stats, 0, zbytes, stream);
    ell_fill<CAPA><<<(E + 255) / 256, 256, 0, stream>>>(eidx, cntA, listA, ovfA, E);
    ell_fill<CAPB><<<(T + 255) / 256, 256, 0, stream>>>(kidx, cntB, listB, ovfB, T);

    // ---- stage A: AtomConv ----
    {
      GatherSrc gs;
      gs.base[0] = vertex; gs.idx[0] = eidx;      // vertex[src]
      gs.base[1] = edge;   gs.idx[1] = nullptr;   // edge[e]
      gs.base[2] = vertex; gs.idx[2] = eidx + E;  // vertex[dst]
      gs.base[3] = nullptr; gs.idx[3] = nullptr;
      pass1_gemm<3><<<bE, 256, 0, stream>>>(gs, WcA, WgA, coreB, gateB, statsA, E);
    }
    statprep<<<1, 128, 0, stream>>>(statsA, g_ac, b_ac, g_ag, b_ag, 1.0f / (float)E);
    seg_gather<CAPA><<<(int)(((size_t)N * 8 + 255) / 256), 256, 0, stream>>>(
        coreB, gateB, statsA, cntA, listA, accum, N);
    ovf_apply<<<16, 256, 0, stream>>>(ovfA, eidx, coreB, gateB, statsA, accum);
    outgemm<<<bN, 256, 0, stream>>>(accum, WoA, vertex, outV, N);

    // ---- stage B: BondConv ----
    {
      GatherSrc gs;
      gs.base[0] = outV;  gs.idx[0] = jidx;  // v_new[j]
      gs.base[1] = edge;  gs.idx[1] = kidx;  // edge[k]
      gs.base[2] = edge;  gs.idx[2] = iidx;  // edge[i]
      gs.base[3] = angle; gs.idx[3] = nullptr;
      pass1_gemm<4><<<bT, 256, 0, stream>>>(gs, WcB, WgB, coreB, gateB, statsB, T);
    }
    statprep<<<1, 128, 0, stream>>>(statsB, g_bc, b_bc, g_bg, b_bg, 1.0f / (float)T);
    seg_gather<CAPB><<<(int)(((size_t)E * 8 + 255) / 256), 256, 0, stream>>>(
        coreB, gateB, statsB, cntB, listB, accum, E);
    ovf_apply<<<16, 256, 0, stream>>>(ovfB, kidx, coreB, gateB, statsB, accum);
    outgemm<<<bE, 256, 0, stream>>>(accum, WoB, edge, outE, E);
  } else {
    // ---- fallback: original atomic-scatter path ----
    size_t zbytes = (RM * 64 + 3 * 512) * 4;
    hipMemsetAsync(accum, 0, zbytes, stream);
    const int sE = (int)(((size_t)E * 8 + 255) / 256);

    {
      GatherSrc gs;
      gs.base[0] = vertex; gs.idx[0] = eidx;
      gs.base[1] = edge;   gs.idx[1] = nullptr;
      gs.base[2] = vertex; gs.idx[2] = eidx + E;
      gs.base[3] = nullptr; gs.idx[3] = nullptr;
      pass1_gemm<3><<<bE, 256, 0, stream>>>(gs, WcA, WgA, coreB, gateB, statsA, E);
    }
    statprep<<<1, 128, 0, stream>>>(statsA, g_ac, b_ac, g_ag, b_ag, 1.0f / (float)E);
    pass2_scatter<<<sE, 256, 0, stream>>>(coreB, gateB, statsA, eidx, accum, E);
    outgemm<<<bN, 256, 0, stream>>>(accum, WoA, vertex, outV, N);

    hipMemsetAsync(accum, 0, (size_t)E * 64 * 4, stream);
    {
      GatherSrc gs;
      gs.base[0] = outV;  gs.idx[0] = jidx;
      gs.base[1] = edge;  gs.idx[1] = kidx;
      gs.base[2] = edge;  gs.idx[2] = iidx;
      gs.base[3] = angle; gs.idx[3] = nullptr;
      pass1_gemm<4><<<bT, 256, 0, stream>>>(gs, WcB, WgB, coreB, gateB, statsB, T);
    }
    statprep<<<1, 128, 0, stream>>>(statsB, g_bc, b_bc, g_bg, b_bg, 1.0f / (float)T);
    pass2_scatter<<<sT, 256, 0, stream>>>(coreB, gateB, statsB, kidx, accum, T);
    outgemm<<<bE, 256, 0, stream>>>(accum, WoB, edge, outE, E);
  }

  // ---- stage C: AngleConv ----
  {
    GatherSrc gs;
    gs.base[0] = outV;  gs.idx[0] = jidx;  // v_new[j]
    gs.base[1] = outE;  gs.idx[1] = kidx;  // e_new[k]
    gs.base[2] = outE;  gs.idx[2] = iidx;  // e_new[i]
    gs.base[3] = angle; gs.idx[3] = nullptr;
    pass1_gemm<4><<<bT, 256, 0, stream>>>(gs, WcC, WgC, coreB, gateB, statsC, T);
  }
  statprep<<<1, 128, 0, stream>>>(statsC, g_nc, b_nc, g_ng, b_ng, 1.0f / (float)T);
  pass2_final<<<sT, 256, 0, stream>>>(coreB, gateB, statsC, angle, outA, T);
}

// Round 3
// 2299.064 us; speedup vs baseline: 2.1296x; 1.2906x over previous
//
#include <hip/hip_runtime.h>

typedef unsigned short u16;
typedef unsigned int u32;
typedef float f32x4 __attribute__((ext_vector_type(4)));
typedef short s8v __attribute__((ext_vector_type(8)));  // 8 x bf16 (4 VGPRs)

#define OVF_CAP 8192

// ---------- bf16 helpers ----------
__device__ __forceinline__ u16 f2bf(float f) {
  u32 u = __float_as_uint(f);
  u32 r = u + 0x7fffu + ((u >> 16) & 1u);
  return (u16)(r >> 16);
}
__device__ __forceinline__ void cvt8(uint4 u, float* f) {
  f[0] = __uint_as_float(u.x << 16);
  f[1] = __uint_as_float(u.x & 0xffff0000u);
  f[2] = __uint_as_float(u.y << 16);
  f[3] = __uint_as_float(u.y & 0xffff0000u);
  f[4] = __uint_as_float(u.z << 16);
  f[5] = __uint_as_float(u.z & 0xffff0000u);
  f[6] = __uint_as_float(u.w << 16);
  f[7] = __uint_as_float(u.w & 0xffff0000u);
}
__device__ __forceinline__ u32 pack2(float a, float b) {
  return (u32)f2bf(a) | ((u32)f2bf(b) << 16);
}

struct GatherSrc {
  const float* base[4];
  const int* idx[4];  // nullptr => identity (row index)
};

// ---------- W prep: fold [Wc|Wg] (Kx64 each, fp32) -> transposed bf16 hi/lo
// planes Wt[c][k], c in [0,128). One-time tiny kernel per stage. ----------
__global__ __launch_bounds__(256) void wprep(const float* __restrict__ Wc,
                                             const float* __restrict__ Wg,
                                             u16* __restrict__ hi,
                                             u16* __restrict__ lo, int K) {
  int idx = blockIdx.x * 256 + threadIdx.x;
  if (idx >= 128 * K) return;
  int c = idx / K, k = idx - c * K;
  float w = (c < 64) ? Wc[(size_t)k * 64 + c] : Wg[(size_t)k * 64 + (c - 64)];
  u16 h = f2bf(w);
  float hf = __uint_as_float((u32)h << 16);
  hi[idx] = h;
  lo[idx] = f2bf(w - hf);
}

// ---------- pass 1 (MFMA): gathered concat GEMM via split-bf16 MFMA ----------
// Tile 128 rows x 128 cols (core|gate), 4 waves in 2x2 grid, K = NSEG*64.
// A split into bf16 hi+lo during staging (XOR-swizzled LDS); W split in prep.
// D = Ah*Wh + Ah*Wl + Al*Wh  (fp32 accum) ~= fp32 GEMM accuracy.
template <int NSEG>
__global__ __launch_bounds__(256) void pass1_mfma(
    GatherSrc gs, const u16* __restrict__ wtHi, const u16* __restrict__ wtLo,
    u16* __restrict__ outC, u16* __restrict__ outG, float* __restrict__ stats,
    int R) {
  constexpr int K = NSEG * 64;
  // 16B-aligned: accessed via uint2 stores and 16B (ds_read_b128) loads
  __shared__ __align__(16) u16 aT[2][128 * 64];  // [hi/lo][row*64+k], 32KB
  __shared__ int rowidx[NSEG][128];
  __shared__ float sstat[2][2][64];

  const int t = threadIdx.x;
  const int e0 = blockIdx.x * 128;
  const int lane = t & 63;
  const int w = t >> 6;
  const int wr = w >> 1, wc = w & 1;
  const int l15 = lane & 15, lq = lane >> 4;
  const int rb = wr * 64, cb = wc * 64;
  char* aHi = (char*)aT;
  char* aLo = aHi + 128 * 64 * 2;

  ((float*)sstat)[t] = 0.0f;
  if (t < 128) {
    int rc = e0 + t;
    if (rc > R - 1) rc = R - 1;
#pragma unroll
    for (int sg = 0; sg < NSEG; ++sg) {
      const int* ip = gs.idx[sg];
      rowidx[sg][t] = ip ? ip[rc] : rc;
    }
  }

  f32x4 acc[4][4];
#pragma unroll
  for (int ri = 0; ri < 4; ++ri)
#pragma unroll
    for (int ci = 0; ci < 4; ++ci) acc[ri][ci] = (f32x4){0.f, 0.f, 0.f, 0.f};

  for (int kt = 0; kt < NSEG; ++kt) {
    __syncthreads();  // aT reuse guard
    const float* base = gs.base[kt];
    // stage 128 rows x 64 k (gathered fp32) -> bf16 hi+lo planes in LDS
#pragma unroll
    for (int i = 0; i < 8; ++i) {
      int s = t + i * 256;
      int r = s >> 4;  // 16 float4 per 64-float row
      int k4 = (s & 15) * 4;
      float4 v = *(const float4*)(base + (size_t)rowidx[kt][r] * 64 + k4);
      u16 h0 = f2bf(v.x), h1 = f2bf(v.y), h2 = f2bf(v.z), h3 = f2bf(v.w);
      float r0 = v.x - __uint_as_float((u32)h0 << 16);
      float r1 = v.y - __uint_as_float((u32)h1 << 16);
      float r2 = v.z - __uint_as_float((u32)h2 << 16);
      float r3 = v.w - __uint_as_float((u32)h3 << 16);
      int off = (r << 7) + (k4 << 1);
      off ^= (r & 7) << 4;  // bank-conflict swizzle (G4); bits>=4 only
      *(uint2*)(aHi + off) =
          make_uint2((u32)h0 | ((u32)h1 << 16), (u32)h2 | ((u32)h3 << 16));
      *(uint2*)(aLo + off) = make_uint2(pack2(r0, r1), pack2(r2, r3));
    }
    __syncthreads();
#pragma unroll
    for (int c2 = 0; c2 < 2; ++c2) {
      const int kloc = c2 * 32 + lq * 8;
      s8v ah[4], al[4];
#pragma unroll
      for (int ri = 0; ri < 4; ++ri) {
        int row = rb + ri * 16 + l15;
        int off = (row << 7) + (kloc << 1);
        off ^= (row & 7) << 4;
        ah[ri] = *(const s8v*)(aHi + off);
        al[ri] = *(const s8v*)(aLo + off);
      }
      const int kk = kt * 64 + kloc;
#pragma unroll
      for (int ci = 0; ci < 4; ++ci) {
        size_t boff = (size_t)(cb + ci * 16 + l15) * K + kk;
        s8v bh = *(const s8v*)(wtHi + boff);  // L2-hot, 16B/lane
        s8v bl = *(const s8v*)(wtLo + boff);
#pragma unroll
        for (int ri = 0; ri < 4; ++ri) {
          acc[ri][ci] = __builtin_amdgcn_mfma_f32_16x16x32_bf16(
              al[ri], bh, acc[ri][ci], 0, 0, 0);
          acc[ri][ci] = __builtin_amdgcn_mfma_f32_16x16x32_bf16(
              ah[ri], bl, acc[ri][ci], 0, 0, 0);
          acc[ri][ci] = __builtin_amdgcn_mfma_f32_16x16x32_bf16(
              ah[ri], bh, acc[ri][ci], 0, 0, 0);
        }
      }
    }
  }

  // epilogue: bf16 store + BN stats. D frag: col=lane&15, row=(lane>>4)*4+reg.
  u16* outp = wc ? outG : outC;
  float lsum[4], lsq[4];
#pragma unroll
  for (int ci = 0; ci < 4; ++ci) {
    lsum[ci] = 0.f;
    lsq[ci] = 0.f;
  }
#pragma unroll
  for (int ri = 0; ri < 4; ++ri) {
#pragma unroll
    for (int rg = 0; rg < 4; ++rg) {
      int row = e0 + rb + ri * 16 + lq * 4 + rg;
      if (row < R) {
#pragma unroll
        for (int ci = 0; ci < 4; ++ci) {
          float v = acc[ri][ci][rg];
          lsum[ci] += v;
          lsq[ci] += v * v;
          outp[(size_t)row * 64 + ci * 16 + l15] = f2bf(v);
        }
      }
    }
  }
#pragma unroll
  for (int ci = 0; ci < 4; ++ci) {
    atomicAdd(&sstat[wc][0][ci * 16 + l15], lsum[ci]);
    atomicAdd(&sstat[wc][1][ci * 16 + l15], lsq[ci]);
  }
  __syncthreads();
  {
    int m2 = t >> 7, s2 = (t >> 6) & 1, c = t & 63;
    atomicAdd(&stats[m2 * 128 + s2 * 64 + c], sstat[m2][s2][c]);
  }
}

// ---------- pass 1 (fp32 VALU) — fallback if ws too small ----------
template <int NSEG>
__global__ __launch_bounds__(256) void pass1_gemm(
    GatherSrc gs, const float* __restrict__ Wc, const float* __restrict__ Wg,
    u16* __restrict__ outC, u16* __restrict__ outG, float* __restrict__ stats,
    int R) {
  __shared__ __align__(16) float msg[64][68];
  __shared__ __align__(16) float wt[64][132];
  __shared__ float sstat[2][2][64];
  __shared__ int rowidx[NSEG][64];

  const int t = threadIdx.x;
  const int e0 = blockIdx.x * 64;

  for (int i = t; i < 256; i += 256) ((float*)sstat)[i] = 0.0f;
  if (t < 64) {
    int rc = e0 + t;
    if (rc > R - 1) rc = R - 1;
#pragma unroll
    for (int sg = 0; sg < NSEG; ++sg) {
      const int* ip = gs.idx[sg];
      rowidx[sg][t] = ip ? ip[rc] : rc;
    }
  }

  float acc[4][8];
#pragma unroll
  for (int r = 0; r < 4; ++r)
#pragma unroll
    for (int j = 0; j < 8; ++j) acc[r][j] = 0.0f;

  const int cg = t & 15;
  const int r0 = (t >> 4) * 4;
  const int c8 = cg * 8;

  for (int kt = 0; kt < NSEG; ++kt) {
    __syncthreads();
    {
      const float* base = gs.base[kt];
#pragma unroll
      for (int i = 0; i < 4; ++i) {
        int s = t + i * 256;
        int r = s >> 4, q4 = (s & 15) * 4;
        *(float4*)&msg[r][q4] =
            *(const float4*)(base + (size_t)rowidx[kt][r] * 64 + q4);
      }
    }
    {
#pragma unroll
      for (int i = 0; i < 8; ++i) {
        int s = t + i * 256;
        int mat = s >> 10;
        int kk = (s >> 4) & 63;
        int q4 = (s & 15) * 4;
        const float* wsrc = (mat ? Wg : Wc) + (size_t)(kt * 64 + kk) * 64 + q4;
        *(float4*)&wt[kk][mat * 64 + q4] = *(const float4*)wsrc;
      }
    }
    __syncthreads();
    for (int k = 0; k < 64; k += 4) {
      float a[4][4];
#pragma unroll
      for (int r = 0; r < 4; ++r)
        *(float4*)&a[r][0] = *(const float4*)&msg[r0 + r][k];
#pragma unroll
      for (int kk = 0; kk < 4; ++kk) {
        float wv[8];
        *(float4*)&wv[0] = *(const float4*)&wt[k + kk][c8];
        *(float4*)&wv[4] = *(const float4*)&wt[k + kk][c8 + 4];
#pragma unroll
        for (int r = 0; r < 4; ++r) {
          float m = a[r][kk];
#pragma unroll
          for (int j = 0; j < 8; ++j) acc[r][j] = fmaf(m, wv[j], acc[r][j]);
        }
      }
    }
  }

  const int mat = cg >> 3;
  const int cb = (cg & 7) * 8;
  u16* outp = mat ? outG : outC;
  float ssum[8], ssq[8];
#pragma unroll
  for (int j = 0; j < 8; ++j) {
    ssum[j] = 0.0f;
    ssq[j] = 0.0f;
  }
#pragma unroll
  for (int r = 0; r < 4; ++r) {
    int row = e0 + r0 + r;
    if (row < R) {
      uint4 u;
      u.x = pack2(acc[r][0], acc[r][1]);
      u.y = pack2(acc[r][2], acc[r][3]);
      u.z = pack2(acc[r][4], acc[r][5]);
      u.w = pack2(acc[r][6], acc[r][7]);
      *(uint4*)(outp + (size_t)row * 64 + cb) = u;
#pragma unroll
      for (int j = 0; j < 8; ++j) {
        ssum[j] += acc[r][j];
        ssq[j] += acc[r][j] * acc[r][j];
      }
    }
  }
#pragma unroll
  for (int j = 0; j < 8; ++j) {
    atomicAdd(&sstat[mat][0][cb + j], ssum[j]);
    atomicAdd(&sstat[mat][1][cb + j], ssq[j]);
  }
  __syncthreads();
  {
    int m2 = t >> 7, s2 = (t >> 6) & 1, c = t & 63;
    atomicAdd(&stats[m2 * 128 + s2 * 64 + c], sstat[m2][s2][c]);
  }
}

// ---------- fold BN stats + gamma/beta into per-col scale/shift ----------
__global__ void statprep(float* __restrict__ stats, const float* __restrict__ gc,
                         const float* __restrict__ bc, const float* __restrict__ gg,
                         const float* __restrict__ bg, float rn) {
  int t = threadIdx.x;
  if (t >= 128) return;
  int mat = t >> 6, c = t & 63;
  float sum = stats[mat * 128 + c];
  float sumsq = stats[mat * 128 + 64 + c];
  float mean = sum * rn;
  float var = sumsq * rn - mean * mean;
  float inv = rsqrtf(var + 1e-5f);
  const float* gp = mat ? gg : gc;
  const float* bp = mat ? bg : bc;
  float scale = gp[c] * inv;
  float shift = bp[c] - mean * scale;
  stats[256 + mat * 128 + c] = scale;
  stats[256 + mat * 128 + 64 + c] = shift;
}

// ---------- ELL build ----------
template <int CAP>
__global__ __launch_bounds__(256) void ell_fill(const int* __restrict__ seg,
                                                int* __restrict__ cnt,
                                                int* __restrict__ list,
                                                int* __restrict__ ovf, int R) {
  int e = blockIdx.x * 256 + threadIdx.x;
  if (e >= R) return;
  int s = seg[e];
  int pos = atomicAdd(&cnt[s], 1);
  if (pos < CAP) {
    list[(size_t)s * CAP + pos] = e;
  } else {
    int o = atomicAdd(&ovf[0], 1);
    if (o < OVF_CAP) ovf[1 + o] = e;
  }
}

// ---------- pass 2 (gather form) ----------
template <int CAP>
__global__ __launch_bounds__(256) void seg_gather(
    const u16* __restrict__ coreB, const u16* __restrict__ gateB,
    const float* __restrict__ stats, const int* __restrict__ cnt,
    const int* __restrict__ list, float* __restrict__ accum, int S) {
  int gid = blockIdx.x * 256 + threadIdx.x;
  int s = gid >> 3;
  if (s >= S) return;
  int cb = (gid & 7) * 8;
  float scC[8], shC[8], scG[8], shG[8];
  *(float4*)&scC[0] = *(const float4*)&stats[256 + cb];
  *(float4*)&scC[4] = *(const float4*)&stats[256 + cb + 4];
  *(float4*)&shC[0] = *(const float4*)&stats[320 + cb];
  *(float4*)&shC[4] = *(const float4*)&stats[320 + cb + 4];
  *(float4*)&scG[0] = *(const float4*)&stats[384 + cb];
  *(float4*)&scG[4] = *(const float4*)&stats[384 + cb + 4];
  *(float4*)&shG[0] = *(const float4*)&stats[448 + cb];
  *(float4*)&shG[4] = *(const float4*)&stats[448 + cb + 4];

  int n = cnt[s];
  if (n > CAP) n = CAP;
  const int* lp = list + (size_t)s * CAP;
  float acc[8];
#pragma unroll
  for (int j = 0; j < 8; ++j) acc[j] = 0.0f;

  int m = 0;
  for (; m + 2 <= n; m += 2) {
    int r0 = lp[m], r1 = lp[m + 1];
    uint4 uc0 = *(const uint4*)(coreB + (size_t)r0 * 64 + cb);
    uint4 ug0 = *(const uint4*)(gateB + (size_t)r0 * 64 + cb);
    uint4 uc1 = *(const uint4*)(coreB + (size_t)r1 * 64 + cb);
    uint4 ug1 = *(const uint4*)(gateB + (size_t)r1 * 64 + cb);
    float c[8], g[8];
    cvt8(uc0, c);
    cvt8(ug0, g);
#pragma unroll
    for (int j = 0; j < 8; ++j) {
      float x = fmaf(c[j], scC[j], shC[j]);
      float sx = x / (1.0f + __expf(-x));
      float y = fmaf(g[j], scG[j], shG[j]);
      float sy = 1.0f / (1.0f + __expf(-y));
      acc[j] += sx * sy;
    }
    cvt8(uc1, c);
    cvt8(ug1, g);
#pragma unroll
    for (int j = 0; j < 8; ++j) {
      float x = fmaf(c[j], scC[j], shC[j]);
      float sx = x / (1.0f + __expf(-x));
      float y = fmaf(g[j], scG[j], shG[j]);
      float sy = 1.0f / (1.0f + __expf(-y));
      acc[j] += sx * sy;
    }
  }
  if (m < n) {
    int r0 = lp[m];
    uint4 uc0 = *(const uint4*)(coreB + (size_t)r0 * 64 + cb);
    uint4 ug0 = *(const uint4*)(gateB + (size_t)r0 * 64 + cb);
    float c[8], g[8];
    cvt8(uc0, c);
    cvt8(ug0, g);
#pragma unroll
    for (int j = 0; j < 8; ++j) {
      float x = fmaf(c[j], scC[j], shC[j]);
      float sx = x / (1.0f + __expf(-x));
      float y = fmaf(g[j], scG[j], shG[j]);
      float sy = 1.0f / (1.0f + __expf(-y));
      acc[j] += sx * sy;
    }
  }
  float* ap = accum + (size_t)s * 64 + cb;
  *(float4*)ap = *(float4*)&acc[0];
  *(float4*)(ap + 4) = *(float4*)&acc[4];
}

// ---------- overflow fallback ----------
__global__ __launch_bounds__(256) void ovf_apply(
    const int* __restrict__ ovf, const int* __restrict__ seg,
    const u16* __restrict__ coreB, const u16* __restrict__ gateB,
    const float* __restrict__ stats, float* __restrict__ accum) {
  int n = ovf[0];
  if (n > OVF_CAP) n = OVF_CAP;
  int total = n * 8;
  for (int gid = blockIdx.x * 256 + threadIdx.x; gid < total;
       gid += gridDim.x * 256) {
    int i = gid >> 3;
    int cb = (gid & 7) * 8;
    int r = ovf[1 + i];
    int s = seg[r];
    uint4 uc = *(const uint4*)(coreB + (size_t)r * 64 + cb);
    uint4 ug = *(const uint4*)(gateB + (size_t)r * 64 + cb);
    float c[8], g[8];
    cvt8(uc, c);
    cvt8(ug, g);
    float* ap = accum + (size_t)s * 64 + cb;
#pragma unroll
    for (int j = 0; j < 8; ++j) {
      float x = fmaf(c[j], stats[256 + cb + j], stats[320 + cb + j]);
      float sx = x / (1.0f + __expf(-x));
      float y = fmaf(g[j], stats[384 + cb + j], stats[448 + cb + j]);
      float sy = 1.0f / (1.0f + __expf(-y));
      atomicAdd(ap + j, sx * sy);
    }
  }
}

// ---------- pass 2 (atomic scatter form) — deep fallback ----------
__global__ __launch_bounds__(256) void pass2_scatter(
    const u16* __restrict__ coreB, const u16* __restrict__ gateB,
    const float* __restrict__ stats, const int* __restrict__ seg,
    float* __restrict__ accum, int R) {
  int gid = blockIdx.x * 256 + threadIdx.x;
  if (gid >= R * 8) return;
  int r = gid >> 3;
  int cb = (gid & 7) * 8;
  uint4 uc = *(const uint4*)(coreB + (size_t)r * 64 + cb);
  uint4 ug = *(const uint4*)(gateB + (size_t)r * 64 + cb);
  float c[8], g[8];
  cvt8(uc, c);
  cvt8(ug, g);
  float scC[8], shC[8], scG[8], shG[8];
  *(float4*)&scC[0] = *(const float4*)&stats[256 + cb];
  *(float4*)&scC[4] = *(const float4*)&stats[256 + cb + 4];
  *(float4*)&shC[0] = *(const float4*)&stats[320 + cb];
  *(float4*)&shC[4] = *(const float4*)&stats[320 + cb + 4];
  *(float4*)&scG[0] = *(const float4*)&stats[384 + cb];
  *(float4*)&scG[4] = *(const float4*)&stats[384 + cb + 4];
  *(float4*)&shG[0] = *(const float4*)&stats[448 + cb];
  *(float4*)&shG[4] = *(const float4*)&stats[448 + cb + 4];
  int sg = seg[r];
  float* ap = accum + (size_t)sg * 64 + cb;
#pragma unroll
  for (int j = 0; j < 8; ++j) {
    float x = fmaf(c[j], scC[j], shC[j]);
    float sx = x / (1.0f + __expf(-x));
    float y = fmaf(g[j], scG[j], shG[j]);
    float sy = 1.0f / (1.0f + __expf(-y));
    atomicAdd(ap + j, sx * sy);
  }
}

// ---------- pass 2 (angle stage): BN-gate + residual -> fp32 out ----------
__global__ __launch_bounds__(256) void pass2_final(
    const u16* __restrict__ coreB, const u16* __restrict__ gateB,
    const float* __restrict__ stats, const float* __restrict__ angle,
    float* __restrict__ outA, int R) {
  int gid = blockIdx.x * 256 + threadIdx.x;
  if (gid >= R * 8) return;
  int r = gid >> 3;
  int cb = (gid & 7) * 8;
  uint4 uc = *(const uint4*)(coreB + (size_t)r * 64 + cb);
  uint4 ug = *(const uint4*)(gateB + (size_t)r * 64 + cb);
  float c[8], g[8], a[8];
  cvt8(uc, c);
  cvt8(ug, g);
  *(float4*)&a[0] = *(const float4*)(angle + (size_t)r * 64 + cb);
  *(float4*)&a[4] = *(const float4*)(angle + (size_t)r * 64 + cb + 4);
  float scC[8], shC[8], scG[8], shG[8];
  *(float4*)&scC[0] = *(const float4*)&stats[256 + cb];
  *(float4*)&scC[4] = *(const float4*)&stats[256 + cb + 4];
  *(float4*)&shC[0] = *(const float4*)&stats[320 + cb];
  *(float4*)&shC[4] = *(const float4*)&stats[320 + cb + 4];
  *(float4*)&scG[0] = *(const float4*)&stats[384 + cb];
  *(float4*)&scG[4] = *(const float4*)&stats[384 + cb + 4];
  *(float4*)&shG[0] = *(const float4*)&stats[448 + cb];
  *(float4*)&shG[4] = *(const float4*)&stats[448 + cb + 4];
  float o[8];
#pragma unroll
  for (int j = 0; j < 8; ++j) {
    float x = fmaf(c[j], scC[j], shC[j]);
    float sx = x / (1.0f + __expf(-x));
    float y = fmaf(g[j], scG[j], shG[j]);
    float sy = 1.0f / (1.0f + __expf(-y));
    o[j] = sx * sy + a[j];
  }
  float* dst = outA + (size_t)r * 64 + cb;
  *(float4*)dst = *(float4*)&o[0];
  *(float4*)(dst + 4) = *(float4*)&o[4];
}

// ---------- small out-GEMM: dest = accum @ W(64x64) + resid ----------
__global__ __launch_bounds__(256) void outgemm(const float* __restrict__ accum,
                                               const float* __restrict__ W,
                                               const float* __restrict__ resid,
                                               float* __restrict__ dest, int R) {
  __shared__ __align__(16) float inl[64][68];
  __shared__ __align__(16) float wl[64][68];
  const int t = threadIdx.x;
  const int e0 = blockIdx.x * 64;
#pragma unroll
  for (int i = 0; i < 4; ++i) {
    int s = t + i * 256;
    int kk = s >> 4, q4 = (s & 15) * 4;
    *(float4*)&wl[kk][q4] = *(const float4*)(W + (size_t)kk * 64 + q4);
  }
#pragma unroll
  for (int i = 0; i < 4; ++i) {
    int s = t + i * 256;
    int r = s >> 4, q4 = (s & 15) * 4;
    int row = e0 + r;
    if (row > R - 1) row = R - 1;
    *(float4*)&inl[r][q4] = *(const float4*)(accum + (size_t)row * 64 + q4);
  }
  __syncthreads();
  const int c4 = (t & 15) * 4;
  const int r0 = (t >> 4) * 4;
  float acc[4][4];
#pragma unroll
  for (int r = 0; r < 4; ++r)
#pragma unroll
    for (int j = 0; j < 4; ++j) acc[r][j] = 0.0f;
  for (int k = 0; k < 64; k += 4) {
    float a[4][4];
#pragma unroll
    for (int r = 0; r < 4; ++r)
      *(float4*)&a[r][0] = *(const float4*)&inl[r0 + r][k];
#pragma unroll
    for (int kk = 0; kk < 4; ++kk) {
      float w[4];
      *(float4*)&w[0] = *(const float4*)&wl[k + kk][c4];
#pragma unroll
      for (int r = 0; r < 4; ++r) {
        float m = a[r][kk];
#pragma unroll
        for (int j = 0; j < 4; ++j) acc[r][j] = fmaf(m, w[j], acc[r][j]);
      }
    }
  }
#pragma unroll
  for (int r = 0; r < 4; ++r) {
    int row = e0 + r0 + r;
    if (row < R) {
      float4 rv = *(const float4*)(resid + (size_t)row * 64 + c4);
      float4 o;
      o.x = acc[r][0] + rv.x;
      o.y = acc[r][1] + rv.y;
      o.z = acc[r][2] + rv.z;
      o.w = acc[r][3] + rv.w;
      *(float4*)(dest + (size_t)row * 64 + c4) = o;
    }
  }
}

extern "C" void kernel_launch(void* const* d_in, const int* in_sizes, int n_in,
                              void* d_out, int out_size, void* d_ws,
                              size_t ws_size, hipStream_t stream) {
  const float* vertex = (const float*)d_in[0];
  const float* edge = (const float*)d_in[1];
  const float* angle = (const float*)d_in[2];
  const int* eidx = (const int*)d_in[3];  // [2,E]: src then dst
  const int* kidx = (const int*)d_in[4];
  const int* iidx = (const int*)d_in[5];
  const int* jidx = (const int*)d_in[6];
  const float* WcA = (const float*)d_in[7];
  const float* WgA = (const float*)d_in[8];
  const float* WoA = (const float*)d_in[9];
  const float* WcB = (const float*)d_in[10];
  const float* WgB = (const float*)d_in[11];
  const float* WoB = (const float*)d_in[12];
  const float* WcC = (const float*)d_in[13];
  const float* WgC = (const float*)d_in[14];
  const float* g_ac = (const float*)d_in[15];
  const float* g_ag = (const float*)d_in[16];
  const float* g_bc = (const float*)d_in[17];
  const float* g_bg = (const float*)d_in[18];
  const float* g_nc = (const float*)d_in[19];
  const float* g_ng = (const float*)d_in[20];
  const float* b_ac = (const float*)d_in[21];
  const float* b_ag = (const float*)d_in[22];
  const float* b_bc = (const float*)d_in[23];
  const float* b_bg = (const float*)d_in[24];
  const float* b_nc = (const float*)d_in[25];
  const float* b_ng = (const float*)d_in[26];

  const int N = in_sizes[0] / 64;
  const int E = in_sizes[1] / 64;
  const int T = in_sizes[2] / 64;

  float* outV = (float*)d_out;
  float* outE = outV + (size_t)N * 64;
  float* outA = outE + (size_t)E * 64;

  size_t RT = (size_t)(E > T ? E : T);
  size_t RM = (size_t)(N > E ? N : E);
  u16* coreB = (u16*)d_ws;
  u16* gateB = coreB + RT * 64;
  float* accum = (float*)(gateB + RT * 64);  // RM x 64 fp32
  float* stats = accum + RM * 64;            // 3 stages x 512 floats
  float* statsA = stats;
  float* statsB = stats + 512;
  float* statsC = stats + 1024;

  const int CAPA = 40;  // src-degree ~ Poisson(12); P(>=40) ~ 1e-10
  const int CAPB = 12;  // k-degree ~ Poisson(1);  P(>=12) ~ 8e-10
  int* cntA = (int*)(stats + 1536);       // N ints
  int* cntB = cntA + N;                   // E ints
  int* ovfA = cntB + E;                   // 1 + OVF_CAP
  int* ovfB = ovfA + (1 + OVF_CAP);       // 1 + OVF_CAP
  int* listA = ovfB + (1 + OVF_CAP);      // N*CAPA (not zeroed)
  int* listB = listA + (size_t)N * CAPA;  // E*CAPB (not zeroed)
  size_t needed_ell = (size_t)((char*)(listB + (size_t)E * CAPB) - (char*)d_ws);

  // split-bf16 W planes (transposed [c][K]) after the ELL lists, 256B-aligned
  size_t waddr = ((size_t)(listB + (size_t)E * CAPB) + 255) & ~(size_t)255;
  u16* wtHiA = (u16*)waddr;
  u16* wtLoA = wtHiA + 128 * 192;
  u16* wtHiB = wtLoA + 128 * 192;
  u16* wtLoB = wtHiB + 128 * 256;
  u16* wtHiC = wtLoB + 128 * 256;
  u16* wtLoC = wtHiC + 128 * 256;
  size_t needed_mfma = (size_t)((char*)(wtLoC + 128 * 256) - (char*)d_ws);

  const int bE = (E + 63) / 64;
  const int bT = (T + 63) / 64;
  const int bN = (N + 63) / 64;
  const int mE = (E + 127) / 128;
  const int mT = (T + 127) / 128;
  const int sT = (int)(((size_t)T * 8 + 255) / 256);

  GatherSrc gsA, gsB, gsC;
  gsA.base[0] = vertex; gsA.idx[0] = eidx;
  gsA.base[1] = edge;   gsA.idx[1] = nullptr;
  gsA.base[2] = vertex; gsA.idx[2] = eidx + E;
  gsA.base[3] = nullptr; gsA.idx[3] = nullptr;
  gsB.base[0] = outV;  gsB.idx[0] = jidx;
  gsB.base[1] = edge;  gsB.idx[1] = kidx;
  gsB.base[2] = edge;  gsB.idx[2] = iidx;
  gsB.base[3] = angle; gsB.idx[3] = nullptr;
  gsC.base[0] = outV;  gsC.idx[0] = jidx;
  gsC.base[1] = outE;  gsC.idx[1] = kidx;
  gsC.base[2] = outE;  gsC.idx[2] = iidx;
  gsC.base[3] = angle; gsC.idx[3] = nullptr;

  if (ws_size >= needed_mfma) {
    // ---- MFMA pass1 + ELL gather pass2 ----
    size_t zbytes = (size_t)((char*)listA - (char*)stats);  // stats+cnt+ovf
    hipMemsetAsync(stats, 0, zbytes, stream);
    wprep<<<(128 * 192 + 255) / 256, 256, 0, stream>>>(WcA, WgA, wtHiA, wtLoA, 192);
    wprep<<<(128 * 256 + 255) / 256, 256, 0, stream>>>(WcB, WgB, wtHiB, wtLoB, 256);
    wprep<<<(128 * 256 + 255) / 256, 256, 0, stream>>>(WcC, WgC, wtHiC, wtLoC, 256);
    ell_fill<CAPA><<<(E + 255) / 256, 256, 0, stream>>>(eidx, cntA, listA, ovfA, E);
    ell_fill<CAPB><<<(T + 255) / 256, 256, 0, stream>>>(kidx, cntB, listB, ovfB, T);

    // stage A
    pass1_mfma<3><<<mE, 256, 0, stream>>>(gsA, wtHiA, wtLoA, coreB, gateB, statsA, E);
    statprep<<<1, 128, 0, stream>>>(statsA, g_ac, b_ac, g_ag, b_ag, 1.0f / (float)E);
    seg_gather<CAPA><<<(int)(((size_t)N * 8 + 255) / 256), 256, 0, stream>>>(
        coreB, gateB, statsA, cntA, listA, accum, N);
    ovf_apply<<<16, 256, 0, stream>>>(ovfA, eidx, coreB, gateB, statsA, accum);
    outgemm<<<bN, 256, 0, stream>>>(accum, WoA, vertex, outV, N);

    // stage B
    pass1_mfma<4><<<mT, 256, 0, stream>>>(gsB, wtHiB, wtLoB, coreB, gateB, statsB, T);
    statprep<<<1, 128, 0, stream>>>(statsB, g_bc, b_bc, g_bg, b_bg, 1.0f / (float)T);
    seg_gather<CAPB><<<(int)(((size_t)E * 8 + 255) / 256), 256, 0, stream>>>(
        coreB, gateB, statsB, cntB, listB, accum, E);
    ovf_apply<<<16, 256, 0, stream>>>(ovfB, kidx, coreB, gateB, statsB, accum);
    outgemm<<<bE, 256, 0, stream>>>(accum, WoB, edge, outE, E);

    // stage C
    pass1_mfma<4><<<mT, 256, 0, stream>>>(gsC, wtHiC, wtLoC, coreB, gateB, statsC, T);
    statprep<<<1, 128, 0, stream>>>(statsC, g_nc, b_nc, g_ng, b_ng, 1.0f / (float)T);
    pass2_final<<<sT, 256, 0, stream>>>(coreB, gateB, statsC, angle, outA, T);
  } else if (ws_size >= needed_ell) {
    // ---- VALU pass1 + ELL gather pass2 ----
    size_t zbytes = (size_t)((char*)listA - (char*)stats);
    hipMemsetAsync(stats, 0, zbytes, stream);
    ell_fill<CAPA><<<(E + 255) / 256, 256, 0, stream>>>(eidx, cntA, listA, ovfA, E);
    ell_fill<CAPB><<<(T + 255) / 256, 256, 0, stream>>>(kidx, cntB, listB, ovfB, T);

    pass1_gemm<3><<<bE, 256, 0, stream>>>(gsA, WcA, WgA, coreB, gateB, statsA, E);
    statprep<<<1, 128, 0, stream>>>(statsA, g_ac, b_ac, g_ag, b_ag, 1.0f / (float)E);
    seg_gather<CAPA><<<(int)(((size_t)N * 8 + 255) / 256), 256, 0, stream>>>(
        coreB, gateB, statsA, cntA, listA, accum, N);
    ovf_apply<<<16, 256, 0, stream>>>(ovfA, eidx, coreB, gateB, statsA, accum);
    outgemm<<<bN, 256, 0, stream>>>(accum, WoA, vertex, outV, N);

    pass1_gemm<4><<<bT, 256, 0, stream>>>(gsB, WcB, WgB, coreB, gateB, statsB, T);
    statprep<<<1, 128, 0, stream>>>(statsB, g_bc, b_bc, g_bg, b_bg, 1.0f / (float)T);
    seg_gather<CAPB><<<(int)(((size_t)E * 8 + 255) / 256), 256, 0, stream>>>(
        coreB, gateB, statsB, cntB, listB, accum, E);
    ovf_apply<<<16, 256, 0, stream>>>(ovfB, kidx, coreB, gateB, statsB, accum);
    outgemm<<<bE, 256, 0, stream>>>(accum, WoB, edge, outE, E);

    pass1_gemm<4><<<bT, 256, 0, stream>>>(gsC, WcC, WgC, coreB, gateB, statsC, T);
    statprep<<<1, 128, 0, stream>>>(statsC, g_nc, b_nc, g_ng, b_ng, 1.0f / (float)T);
    pass2_final<<<sT, 256, 0, stream>>>(coreB, gateB, statsC, angle, outA, T);
  } else {
    // ---- deep fallback: VALU pass1 + atomic scatter ----
    size_t zbytes = (RM * 64 + 3 * 512) * 4;
    hipMemsetAsync(accum, 0, zbytes, stream);
    const int sE = (int)(((size_t)E * 8 + 255) / 256);

    pass1_gemm<3><<<bE, 256, 0, stream>>>(gsA, WcA, WgA, coreB, gateB, statsA, E);
    statprep<<<1, 128, 0, stream>>>(statsA, g_ac, b_ac, g_ag, b_ag, 1.0f / (float)E);
    pass2_scatter<<<sE, 256, 0, stream>>>(coreB, gateB, statsA, eidx, accum, E);
    outgemm<<<bN, 256, 0, stream>>>(accum, WoA, vertex, outV, N);

    hipMemsetAsync(accum, 0, (size_t)E * 64 * 4, stream);
    pass1_gemm<4><<<bT, 256, 0, stream>>>(gsB, WcB, WgB, coreB, gateB, statsB, T);
    statprep<<<1, 128, 0, stream>>>(statsB, g_bc, b_bc, g_bg, b_bg, 1.0f / (float)T);
    pass2_scatter<<<sT, 256, 0, stream>>>(coreB, gateB, statsB, kidx, accum, T);
    outgemm<<<bE, 256, 0, stream>>>(accum, WoB, edge, outE, E);

    pass1_gemm<4><<<bT, 256, 0, stream>>>(gsC, WcC, WgC, coreB, gateB, statsC, T);
    statprep<<<1, 128, 0, stream>>>(statsC, g_nc, b_nc, g_ng, b_ng, 1.0f / (float)T);
    pass2_final<<<sT, 256, 0, stream>>>(coreB, gateB, statsC, angle, outA, T);
  }
}